// Round 5
// baseline (70.467 us; speedup 1.0000x reference)
//
#include <hip/hip_runtime.h>
#include <math.h>

#define BB 4096
#define CC 1000
#define DD 1024
#define NRB 256            // row blocks (16 rows each); block NRB sorts
#define NBLK (NRB + 1)     // total blocks
#define NCOPY 16           // rotated S copies to spread atomics
#define NPH2 250           // phase-2 blocks (4 classes per block, 1 per wave)
#define SCALEF 100.0f

__device__ inline float wred(float v) {
#pragma unroll
    for (int o = 32; o > 0; o >>= 1) v += __shfl_down(v, o);
    return v;
}

__device__ inline float dot4(float4 a, float4 b) {
    return a.x * b.x + a.y * b.y + a.z * b.z + a.w * b.w;
}

union SharedU {
    struct { unsigned short tgt[BB]; unsigned short ord[BB]; int cnt[1024]; int start[1024]; int wsum[4]; } sort; // 24KB
    struct { float accW[4][DD]; } rows;                                                                           // 16KB
    struct { float S[DD]; float red2[4]; } ph2;                                                                   // 4KB
};

__global__ __launch_bounds__(256, 2) void k_mono(const float* __restrict__ feature,
                                                 const float* __restrict__ query,
                                                 const int* __restrict__ target,
                                                 float* __restrict__ S16,
                                                 float* __restrict__ accp,
                                                 unsigned int* __restrict__ c1,
                                                 unsigned int* __restrict__ c2,
                                                 float* __restrict__ p,
                                                 int* __restrict__ order,
                                                 int* __restrict__ startsg,
                                                 int* __restrict__ cntsg,
                                                 float* __restrict__ out) {
    __shared__ SharedU u;
    int tid = threadIdx.x, lane = tid & 63, wv = tid >> 6, bid = blockIdx.x;

    // ===================== Phase 1 =====================
    if (bid == NRB) {
        // ---- stable counting sort of target ----
        for (int i = tid; i < 1024; i += 256) u.sort.cnt[i] = 0;
        for (int i = tid; i < BB; i += 256) u.sort.tgt[i] = (unsigned short)target[i];
        __syncthreads();
        for (int i = tid; i < BB; i += 256) atomicAdd(&u.sort.cnt[u.sort.tgt[i]], 1);
        __syncthreads();
        int b4 = tid * 4;
        int c0 = u.sort.cnt[b4], c1v = u.sort.cnt[b4 + 1], c2v = u.sort.cnt[b4 + 2], c3 = u.sort.cnt[b4 + 3];
        int tot = c0 + c1v + c2v + c3;
        int inc = tot;
#pragma unroll
        for (int off = 1; off < 64; off <<= 1) {
            int t = __shfl_up(inc, off);
            if (lane >= off) inc += t;
        }
        if (lane == 63) u.sort.wsum[wv] = inc;
        __syncthreads();
        int wpre = 0;
        for (int w = 0; w < wv; ++w) wpre += u.sort.wsum[w];
        int excl = wpre + inc - tot;
        u.sort.start[b4] = excl;
        u.sort.start[b4 + 1] = excl + c0;
        u.sort.start[b4 + 2] = excl + c0 + c1v;
        u.sort.start[b4 + 3] = excl + c0 + c1v + c2v;
        u.sort.cnt[b4] = 0; u.sort.cnt[b4 + 1] = 0; u.sort.cnt[b4 + 2] = 0; u.sort.cnt[b4 + 3] = 0;
        __syncthreads();
        for (int i = tid; i < BB; i += 256) {
            int c = u.sort.tgt[i];
            int j = atomicAdd(&u.sort.cnt[c], 1);
            u.sort.ord[u.sort.start[c] + j] = (unsigned short)i;
        }
        __syncthreads();
        for (int c = tid; c < 1024; c += 256) {
            int s = u.sort.start[c], n = u.sort.cnt[c];
            for (int a = 1; a < n; ++a) {
                unsigned short key = u.sort.ord[s + a];
                int j = a - 1;
                while (j >= 0 && u.sort.ord[s + j] > key) { u.sort.ord[s + j + 1] = u.sort.ord[s + j]; --j; }
                u.sort.ord[s + j + 1] = key;
            }
        }
        __syncthreads();
        for (int i = tid; i < BB; i += 256) order[i] = (int)u.sort.ord[i];
        for (int c = tid; c < 1024; c += 256) { startsg[c] = u.sort.start[c]; cntsg[c] = u.sort.cnt[c]; }
    } else {
        // ---- 16 rows per block; wave wv owns rows b0..b0+3, full-row in-wave ----
        float4 acc[4];
#pragma unroll
        for (int k = 0; k < 4; ++k) acc[k] = make_float4(0.f, 0.f, 0.f, 0.f);
        int b0 = bid * 16 + wv * 4;
#pragma unroll
        for (int r = 0; r < 4; ++r) {
            int b = b0 + r;
            int tb = target[b];
            const float4* fr = (const float4*)(feature + (size_t)b * DD);
            const float4* qr = (const float4*)(query + (size_t)tb * DD);
            float4 x[4], q[4];
#pragma unroll
            for (int k = 0; k < 4; ++k) { x[k] = fr[lane + 64 * k]; q[k] = qr[lane + 64 * k]; }
            float nf = 0.f, nq = 0.f, dt = 0.f;
#pragma unroll
            for (int k = 0; k < 4; ++k) {
                nf += dot4(x[k], x[k]);
                nq += dot4(q[k], q[k]);
                dt += dot4(x[k], q[k]);
            }
            nf = wred(nf); nq = wred(nq); dt = wred(dt);
            nf = __shfl(nf, 0); nq = __shfl(nq, 0); dt = __shfl(dt, 0);
            float rn = rsqrtf(nf);
            if (lane == 0) p[b] = dt * rn * rsqrtf(nq);
#pragma unroll
            for (int k = 0; k < 4; ++k) {
                acc[k].x += x[k].x * rn; acc[k].y += x[k].y * rn;
                acc[k].z += x[k].z * rn; acc[k].w += x[k].w * rn;
            }
        }
#pragma unroll
        for (int k = 0; k < 4; ++k)
            ((float4*)&u.rows.accW[wv][0])[lane + 64 * k] = acc[k];
        __syncthreads();
        float* dst = S16 + (size_t)(bid & (NCOPY - 1)) * DD;
        for (int d = tid; d < DD; d += 256) {
            float v = u.rows.accW[0][d] + u.rows.accW[1][d] + u.rows.accW[2][d] + u.rows.accW[3][d];
            atomicAdd(&dst[d], v);
        }
    }

    // ===================== device-wide barrier (all NBLK co-resident) =====================
    __threadfence();
    __syncthreads();
    if (tid == 0) {
        __hip_atomic_fetch_add(c1, 1u, __ATOMIC_RELEASE, __HIP_MEMORY_SCOPE_AGENT);
        while (__hip_atomic_load(c1, __ATOMIC_ACQUIRE, __HIP_MEMORY_SCOPE_AGENT) < (unsigned int)NBLK)
            __builtin_amdgcn_s_sleep(2);
    }
    __syncthreads();

    // ===================== Phase 2: 4 classes per block, one per wave =====================
    if (bid >= NPH2) return;

    {   // reduce 16 S copies into LDS
        const float4* S16f4 = (const float4*)S16;
        float4 s = make_float4(0.f, 0.f, 0.f, 0.f);
#pragma unroll
        for (int k = 0; k < NCOPY; ++k) {
            float4 v = S16f4[k * 256 + tid];
            s.x += v.x; s.y += v.y; s.z += v.z; s.w += v.w;
        }
        ((float4*)u.ph2.S)[tid] = s;
    }
    __syncthreads();

    int c = bid * 4 + wv;
    const float4* qr = (const float4*)(query + (size_t)c * DD);
    float nq = 0.f, dt = 0.f;
#pragma unroll
    for (int k = 0; k < 4; ++k) {
        float4 q = qr[lane + 64 * k];
        float4 s = ((const float4*)u.ph2.S)[lane + 64 * k];
        nq += dot4(q, q);
        dt += dot4(q, s);
    }
    nq = wred(nq); dt = wred(dt);
    nq = __shfl(nq, 0); dt = __shfl(dt, 0);
    float nn = (10.0f / (float)BB) * dt * rsqrtf(nq);

    int s0 = startsg[c], n = cntsg[c];
    float part = 0.f;
    for (int j = lane; j < n; j += 64) {
        int i = order[s0 + j];      // sample with target == c
        int oi = order[i];          // perm[i]
        float d = SCALEF * (nn - p[oi]);
        part += (d > 0.f) ? (d + log1pf(expf(-d))) : log1pf(expf(d));
    }
    part = wred(part);
    if (lane == 0) u.ph2.red2[wv] = part;
    __syncthreads();
    if (tid == 0) {
        float tot = u.ph2.red2[0] + u.ph2.red2[1] + u.ph2.red2[2] + u.ph2.red2[3];
        atomicAdd(accp, tot);
        __threadfence();
        unsigned int old = atomicAdd(c2, 1u);
        if (old == (unsigned int)(NPH2 - 1)) {
            float a = __hip_atomic_load(accp, __ATOMIC_ACQUIRE, __HIP_MEMORY_SCOPE_AGENT);
            out[0] = a / (float)BB;
        }
    }
}

extern "C" void kernel_launch(void* const* d_in, const int* in_sizes, int n_in,
                              void* d_out, int out_size, void* d_ws, size_t ws_size,
                              hipStream_t stream) {
    const float* feature = (const float*)d_in[0];
    const float* query   = (const float*)d_in[1];
    const int*   target  = (const int*)d_in[2];
    float* out = (float*)d_out;
    float* ws  = (float*)d_ws;

    float*        S16     = ws;                          // 16*1024 floats (64KB)
    float*        accp    = ws + 16384;                  // 1 float
    unsigned int* c1      = (unsigned int*)(ws + 16385); // barrier counter
    unsigned int* c2      = (unsigned int*)(ws + 16386); // done counter
    float*        p       = ws + 16400;                  // 4096 floats
    int*          order   = (int*)(ws + 20496);          // 4096 ints
    int*          startsg = (int*)(ws + 24592);          // 1024 ints
    int*          cntsg   = (int*)(ws + 25616);          // 1024 ints

    hipMemsetAsync(ws, 0, (16384 + 3) * sizeof(float), stream);  // S16 + acc + counters
    k_mono<<<NBLK, 256, 0, stream>>>(feature, query, target, S16, accp, c1, c2,
                                     p, order, startsg, cntsg, out);
}

// Round 6
// 31.874 us; speedup vs baseline: 2.2108x; 2.2108x over previous
//
#include <hip/hip_runtime.h>
#include <math.h>

#define BB 4096
#define CC 1000
#define DD 1024
#define NRB 512            // K1 row blocks (8 rows each; 2 rows/wave); block NRB sorts
#define SCALEF 100.0f

__device__ inline float wred(float v) {
#pragma unroll
    for (int o = 32; o > 0; o >>= 1) v += __shfl_down(v, o);
    return v;
}

__device__ inline float dot4(float4 a, float4 b) {
    return a.x * b.x + a.y * b.y + a.z * b.z + a.w * b.w;
}

union K1Shared {
    float accW[4][DD];  // 16KB: per-wave partial column sums
    struct {
        unsigned short tgt[BB];   // 8KB
        unsigned short ord[BB];   // 8KB
        int cnt[1024];            // 4KB
        int start[1024];          // 4KB
        int wsum[4];
    } sort;                       // ~24.6KB
};

// K1: blocks 0..NRB-1: p[b]=cos(f_b,q_{t_b}); block partial of S written
// contiguously to part[bid][0..DD). Block NRB: stable counting sort.
__global__ __launch_bounds__(256) void k1(const float* __restrict__ feature,
                                          const float* __restrict__ query,
                                          const int* __restrict__ target,
                                          float* __restrict__ p,
                                          float* __restrict__ part,
                                          int* __restrict__ order,
                                          int* __restrict__ startsg,
                                          int* __restrict__ cntsg) {
    __shared__ K1Shared u;
    int tid = threadIdx.x, lane = tid & 63, wv = tid >> 6, bid = blockIdx.x;

    if (bid == NRB) {
        // ---- stable counting sort of target -> order, starts, cnts ----
        for (int i = tid; i < 1024; i += 256) u.sort.cnt[i] = 0;
        for (int i = tid; i < BB; i += 256) u.sort.tgt[i] = (unsigned short)target[i];
        __syncthreads();
        for (int i = tid; i < BB; i += 256) atomicAdd(&u.sort.cnt[u.sort.tgt[i]], 1);
        __syncthreads();
        int b4 = tid * 4;
        int c0 = u.sort.cnt[b4], c1v = u.sort.cnt[b4 + 1], c2v = u.sort.cnt[b4 + 2], c3 = u.sort.cnt[b4 + 3];
        int tot = c0 + c1v + c2v + c3;
        int inc = tot;
#pragma unroll
        for (int off = 1; off < 64; off <<= 1) {
            int t = __shfl_up(inc, off);
            if (lane >= off) inc += t;
        }
        if (lane == 63) u.sort.wsum[wv] = inc;
        __syncthreads();
        int wpre = 0;
        for (int w = 0; w < wv; ++w) wpre += u.sort.wsum[w];
        int excl = wpre + inc - tot;
        u.sort.start[b4] = excl;
        u.sort.start[b4 + 1] = excl + c0;
        u.sort.start[b4 + 2] = excl + c0 + c1v;
        u.sort.start[b4 + 3] = excl + c0 + c1v + c2v;
        u.sort.cnt[b4] = 0; u.sort.cnt[b4 + 1] = 0; u.sort.cnt[b4 + 2] = 0; u.sort.cnt[b4 + 3] = 0;
        __syncthreads();
        for (int i = tid; i < BB; i += 256) {
            int c = u.sort.tgt[i];
            int j = atomicAdd(&u.sort.cnt[c], 1);
            u.sort.ord[u.sort.start[c] + j] = (unsigned short)i;
        }
        __syncthreads();
        for (int c = tid; c < 1024; c += 256) {
            int s = u.sort.start[c], n = u.sort.cnt[c];
            for (int a = 1; a < n; ++a) {
                unsigned short key = u.sort.ord[s + a];
                int j = a - 1;
                while (j >= 0 && u.sort.ord[s + j] > key) { u.sort.ord[s + j + 1] = u.sort.ord[s + j]; --j; }
                u.sort.ord[s + j + 1] = key;
            }
        }
        __syncthreads();
        for (int i = tid; i < BB; i += 256) order[i] = (int)u.sort.ord[i];
        for (int c = tid; c < 1024; c += 256) { startsg[c] = u.sort.start[c]; cntsg[c] = u.sort.cnt[c]; }
        return;
    }

    // ---- row blocks: wave wv owns rows b0,b0+1 entirely; no syncs in row path ----
    float4 acc[4];
#pragma unroll
    for (int k = 0; k < 4; ++k) acc[k] = make_float4(0.f, 0.f, 0.f, 0.f);
    int b0 = bid * 8 + wv * 2;
#pragma unroll
    for (int r = 0; r < 2; ++r) {
        int b = b0 + r;
        int tb = target[b];
        const float4* fr = (const float4*)(feature + (size_t)b * DD);
        const float4* qr = (const float4*)(query + (size_t)tb * DD);
        float4 x[4], q[4];
#pragma unroll
        for (int k = 0; k < 4; ++k) { x[k] = fr[lane + 64 * k]; q[k] = qr[lane + 64 * k]; }
        float nf = 0.f, nq = 0.f, dt = 0.f;
#pragma unroll
        for (int k = 0; k < 4; ++k) {
            nf += dot4(x[k], x[k]);
            nq += dot4(q[k], q[k]);
            dt += dot4(x[k], q[k]);
        }
        nf = wred(nf); nq = wred(nq); dt = wred(dt);
        nf = __shfl(nf, 0); nq = __shfl(nq, 0); dt = __shfl(dt, 0);
        float rn = rsqrtf(nf);
        if (lane == 0) p[b] = dt * rn * rsqrtf(nq);
#pragma unroll
        for (int k = 0; k < 4; ++k) {
            acc[k].x += x[k].x * rn; acc[k].y += x[k].y * rn;
            acc[k].z += x[k].z * rn; acc[k].w += x[k].w * rn;
        }
    }
#pragma unroll
    for (int k = 0; k < 4; ++k)
        ((float4*)&u.accW[wv][0])[lane + 64 * k] = acc[k];
    __syncthreads();
    // block combine + contiguous store (full cache lines, no amplification)
    {
        float4 a0 = ((const float4*)u.accW[0])[tid];
        float4 a1 = ((const float4*)u.accW[1])[tid];
        float4 a2 = ((const float4*)u.accW[2])[tid];
        float4 a3 = ((const float4*)u.accW[3])[tid];
        float4 s;
        s.x = a0.x + a1.x + a2.x + a3.x;
        s.y = a0.y + a1.y + a2.y + a3.y;
        s.z = a0.z + a1.z + a2.z + a3.z;
        s.w = a0.w + a1.w + a2.w + a3.w;
        ((float4*)part)[bid * 256 + tid] = s;
    }
}

// K2: part[512][1024] -> part2[16][1024] (each block sums 32 contiguous rows)
__global__ __launch_bounds__(256) void k2(const float* __restrict__ part,
                                          float* __restrict__ part2) {
    const float4* part4 = (const float4*)part;
    int g = blockIdx.x, tid = threadIdx.x;
    float4 a = make_float4(0.f, 0.f, 0.f, 0.f);
#pragma unroll 8
    for (int blk = g * 32; blk < g * 32 + 32; ++blk) {
        float4 v = part4[blk * 256 + tid];
        a.x += v.x; a.y += v.y; a.z += v.z; a.w += v.w;
    }
    ((float4*)part2)[g * 256 + tid] = a;
}

// K3: block c: S (in-register from part2), nnval[c], class-c softplus partial -> lossp[c]
__global__ __launch_bounds__(256) void k3(const float* __restrict__ query,
                                          const float* __restrict__ part2,
                                          const float* __restrict__ p,
                                          const int* __restrict__ order,
                                          const int* __restrict__ startsg,
                                          const int* __restrict__ cntsg,
                                          float* __restrict__ lossp) {
    __shared__ float red[4][2];
    __shared__ float rbc[4];
    int c = blockIdx.x, tid = threadIdx.x, lane = tid & 63, wv = tid >> 6;

    const float4* p2 = (const float4*)part2;
    float4 s = make_float4(0.f, 0.f, 0.f, 0.f);
#pragma unroll
    for (int k = 0; k < 16; ++k) {
        float4 v = p2[k * 256 + tid];
        s.x += v.x; s.y += v.y; s.z += v.z; s.w += v.w;
    }
    float4 q = ((const float4*)(query + (size_t)c * DD))[tid];
    float nq = dot4(q, q);
    float dt = dot4(q, s);
    nq = wred(nq); dt = wred(dt);
    if (lane == 0) { red[wv][0] = nq; red[wv][1] = dt; }
    __syncthreads();
    nq = red[0][0] + red[1][0] + red[2][0] + red[3][0];
    dt = red[0][1] + red[1][1] + red[2][1] + red[3][1];
    float nn = (10.0f / (float)BB) * dt * rsqrtf(nq);

    int s0 = startsg[c], n = cntsg[c];
    float partl = 0.f;
    for (int j = tid; j < n; j += 256) {
        int i = order[s0 + j];   // sample with target == c  (== sorted position set)
        int oi = order[i];       // perm[i]
        float d = SCALEF * (nn - p[oi]);
        partl += (d > 0.f) ? (d + log1pf(expf(-d))) : log1pf(expf(d));
    }
    partl = wred(partl);
    if (lane == 0) rbc[wv] = partl;
    __syncthreads();
    if (tid == 0) lossp[c] = rbc[0] + rbc[1] + rbc[2] + rbc[3];
}

// K4: out = sum(lossp)/B
__global__ __launch_bounds__(256) void k4(const float* __restrict__ lossp,
                                          float* __restrict__ out) {
    __shared__ float rbc[4];
    int tid = threadIdx.x, lane = tid & 63, wv = tid >> 6;
    float a = 0.f;
    for (int j = tid; j < CC; j += 256) a += lossp[j];
    a = wred(a);
    if (lane == 0) rbc[wv] = a;
    __syncthreads();
    if (tid == 0) out[0] = (rbc[0] + rbc[1] + rbc[2] + rbc[3]) / (float)BB;
}

extern "C" void kernel_launch(void* const* d_in, const int* in_sizes, int n_in,
                              void* d_out, int out_size, void* d_ws, size_t ws_size,
                              hipStream_t stream) {
    const float* feature = (const float*)d_in[0];
    const float* query   = (const float*)d_in[1];
    const int*   target  = (const int*)d_in[2];
    float* out = (float*)d_out;
    float* ws  = (float*)d_ws;

    float* p       = ws;                      // 4096
    int*   order   = (int*)(ws + 4096);       // 4096
    int*   startsg = (int*)(ws + 8192);       // 1024
    int*   cntsg   = (int*)(ws + 9216);       // 1024
    float* lossp   = ws + 10240;              // 1024 (1000 used)
    float* part    = ws + 16384;              // 512*1024 floats (2MB)
    float* part2   = ws + 16384 + 512 * 1024; // 16*1024 floats

    k1<<<NRB + 1, 256, 0, stream>>>(feature, query, target, p, part, order, startsg, cntsg);
    k2<<<16, 256, 0, stream>>>(part, part2);
    k3<<<CC, 256, 0, stream>>>(query, part2, p, order, startsg, cntsg, lossp);
    k4<<<1, 256, 0, stream>>>(lossp, out);
}